// Round 2
// baseline (1089.955 us; speedup 1.0000x reference)
//
#include <hip/hip_runtime.h>
#include <hip/hip_bf16.h>

typedef unsigned short u16;
typedef unsigned int u32;

#define NN 4096      // graph nodes
#define MQ 2048      // query rows
#define QDIM 32
#define IND 257      // 2*128+1
#define KW 8224      // 32*257
#define KP 8256      // KW + 32 bias rows (q@b folded in)
#define CATP 320     // padded concat width (5 * 64)
#define HD 128
#define XD 129

__device__ __forceinline__ float bf2f(u16 u){ return __uint_as_float(((u32)u)<<16); }
__device__ __forceinline__ u16 f2bf(float f){
    u32 x = __float_as_uint(f);
    return (u16)((x + 0x7fffu + ((x>>16)&1u)) >> 16);
}

// ---------------- pack concat([x,h]) into padded f32 [NN][CATP] ----------------
__global__ __launch_bounds__(256) void k_pack_cat(const float* __restrict__ x,
                                                  const float* __restrict__ h,
                                                  float* __restrict__ cat){
    int id = blockIdx.x*256 + threadIdx.x;     // grid covers exactly NN*CATP
    int row = id / CATP, c = id - row*CATP;
    float v = 0.f;
    if (c < XD) v = x[row*XD + c];
    else if (c < IND) v = h[row*HD + (c - XD)];
    cat[id] = v;
}

// ---------------- conv GEMM: cg[m, 0:320] = sum_k adj[idx[m],k] * cat[k,:] ------
// BM=32, BN=64, BK=32, 256 threads, 2x4 micro-tile, f32 accumulate
__global__ __launch_bounds__(256) void k_conv_gemm(const float* __restrict__ adj,
                                                   const float* __restrict__ cat,
                                                   const int* __restrict__ idx,
                                                   float* __restrict__ cg){
    __shared__ float As[32][34];   // [k][m]
    __shared__ float Bs[32][68];   // [k][j]
    __shared__ int rows[32];
    const int tid = threadIdx.x;
    const int m0 = blockIdx.y*32, j0 = blockIdx.x*64;
    if (tid < 32) rows[tid] = idx[m0 + tid];
    __syncthreads();
    const int ty = tid >> 4, tx = tid & 15;
    const int la_m = tid >> 3, la_k = (tid & 7)*4;
    const int lb_k = tid >> 3, lb_j = (tid & 7)*8;
    float acc[2][4] = {};
    for (int k0 = 0; k0 < NN; k0 += 32){
        float4 av = *reinterpret_cast<const float4*>(adj + (size_t)rows[la_m]*NN + k0 + la_k);
        As[la_k + 0][la_m] = av.x;
        As[la_k + 1][la_m] = av.y;
        As[la_k + 2][la_m] = av.z;
        As[la_k + 3][la_m] = av.w;
        const float* bsrc = cat + (size_t)(k0 + lb_k)*CATP + j0 + lb_j;
        float4 b0v = *reinterpret_cast<const float4*>(bsrc);
        float4 b1v = *reinterpret_cast<const float4*>(bsrc + 4);
        Bs[lb_k][lb_j + 0] = b0v.x; Bs[lb_k][lb_j + 1] = b0v.y;
        Bs[lb_k][lb_j + 2] = b0v.z; Bs[lb_k][lb_j + 3] = b0v.w;
        Bs[lb_k][lb_j + 4] = b1v.x; Bs[lb_k][lb_j + 5] = b1v.y;
        Bs[lb_k][lb_j + 6] = b1v.z; Bs[lb_k][lb_j + 7] = b1v.w;
        __syncthreads();
        #pragma unroll
        for (int kk = 0; kk < 32; ++kk){
            float a0 = As[kk][ty*2+0], a1 = As[kk][ty*2+1];
            float b0 = Bs[kk][tx*4+0], b1 = Bs[kk][tx*4+1];
            float b2 = Bs[kk][tx*4+2], b3 = Bs[kk][tx*4+3];
            acc[0][0] += a0*b0; acc[0][1] += a0*b1; acc[0][2] += a0*b2; acc[0][3] += a0*b3;
            acc[1][0] += a1*b0; acc[1][1] += a1*b1; acc[1][2] += a1*b2; acc[1][3] += a1*b3;
        }
        __syncthreads();
    }
    #pragma unroll
    for (int r = 0; r < 2; ++r)
        #pragma unroll
        for (int c = 0; c < 4; ++c)
            cg[(size_t)(m0 + ty*2 + r)*CATP + j0 + tx*4 + c] = acc[r][c];
}

// ---------------- build P1: P[n,k] = bf16( q[n, k/257] * cg[n, k%257] ), tail = q
__global__ __launch_bounds__(256) void k_build_p1(const float* __restrict__ q,
                                                  const float* __restrict__ cg,
                                                  u16* __restrict__ P){
    int k = blockIdx.x*256 + threadIdx.x;
    if (k >= KP) return;
    int n = blockIdx.y;
    float val;
    if (k < KW){
        int d = k / 257;            // compile-time-const divisor -> magic mul
        int i = k - d*257;
        val = q[n*QDIM + d] * cg[(size_t)n*CATP + i];
    } else {
        val = q[n*QDIM + (k - KW)];
    }
    P[(size_t)n*KP + k] = f2bf(val);
}

// ---------------- build P2 from cn = [x[idx[n]], h_upd[n]] -----------------------
__global__ __launch_bounds__(256) void k_build_p2(const float* __restrict__ q,
                                                  const float* __restrict__ x,
                                                  const int* __restrict__ idx,
                                                  const float* __restrict__ h_upd,
                                                  u16* __restrict__ P){
    int k = blockIdx.x*256 + threadIdx.x;
    if (k >= KP) return;
    int n = blockIdx.y;
    float val;
    if (k < KW){
        int d = k / 257;
        int i = k - d*257;
        float f = (i < XD) ? x[(size_t)idx[n]*XD + i] : h_upd[n*HD + (i - XD)];
        val = q[n*QDIM + d] * f;
    } else {
        val = q[n*QDIM + (k - KW)];
    }
    P[(size_t)n*KP + k] = f2bf(val);
}

// ---------------- gate GEMM: out[m, bx*64 + :64] = P @ Wsel (K = 8256) -----------
// bx in {0,1} -> (Wa,ba); bx in {2,3} -> (Wb,bb); bias rows come from b at k>=KW.
__global__ __launch_bounds__(256) void k_gate_gemm(const u16* __restrict__ P,
                                                   const float* __restrict__ Wa,
                                                   const float* __restrict__ ba,
                                                   const float* __restrict__ Wb,
                                                   const float* __restrict__ bb,
                                                   float* __restrict__ out, int ldout){
    __shared__ float As[32][34];
    __shared__ float Bs[32][68];
    const int tid = threadIdx.x;
    const int bx = blockIdx.x;
    const float* W  = (bx >= 2) ? Wb : Wa;
    const float* bi = (bx >= 2) ? bb : ba;
    const int jb = (bx & 1)*64;
    const int m0 = blockIdx.y*32;
    const int ty = tid >> 4, tx = tid & 15;
    const int la_m = tid >> 3, la_k = (tid & 7)*4;
    const int lb_k = tid >> 3, lb_j = (tid & 7)*8;
    float acc[2][4] = {};
    for (int k0 = 0; k0 < KP; k0 += 32){
        uint2 av = *reinterpret_cast<const uint2*>(P + (size_t)(m0 + la_m)*KP + k0 + la_k);
        const u16* ap = reinterpret_cast<const u16*>(&av);
        #pragma unroll
        for (int j = 0; j < 4; ++j) As[la_k + j][la_m] = bf2f(ap[j]);
        int gk = k0 + lb_k;
        const float* bsrc = (gk < KW) ? (W + (size_t)gk*HD + jb + lb_j)
                                      : (bi + (size_t)(gk - KW)*HD + jb + lb_j);
        float4 b0v = *reinterpret_cast<const float4*>(bsrc);
        float4 b1v = *reinterpret_cast<const float4*>(bsrc + 4);
        Bs[lb_k][lb_j + 0] = b0v.x; Bs[lb_k][lb_j + 1] = b0v.y;
        Bs[lb_k][lb_j + 2] = b0v.z; Bs[lb_k][lb_j + 3] = b0v.w;
        Bs[lb_k][lb_j + 4] = b1v.x; Bs[lb_k][lb_j + 5] = b1v.y;
        Bs[lb_k][lb_j + 6] = b1v.z; Bs[lb_k][lb_j + 7] = b1v.w;
        __syncthreads();
        #pragma unroll
        for (int kk = 0; kk < 32; ++kk){
            float a0 = As[kk][ty*2+0], a1 = As[kk][ty*2+1];
            float b0 = Bs[kk][tx*4+0], b1 = Bs[kk][tx*4+1];
            float b2 = Bs[kk][tx*4+2], b3 = Bs[kk][tx*4+3];
            acc[0][0] += a0*b0; acc[0][1] += a0*b1; acc[0][2] += a0*b2; acc[0][3] += a0*b3;
            acc[1][0] += a1*b0; acc[1][1] += a1*b1; acc[1][2] += a1*b2; acc[1][3] += a1*b3;
        }
        __syncthreads();
    }
    #pragma unroll
    for (int r = 0; r < 2; ++r)
        #pragma unroll
        for (int c = 0; c < 4; ++c)
            out[(size_t)(m0 + ty*2 + r)*ldout + bx*64 + tx*4 + c] = acc[r][c];
}

// ---------------- act1: r,u = sigmoid; h_upd = r * h[idx] ------------------------
__global__ __launch_bounds__(256) void k_act1(const float* __restrict__ S1,
                                              const float* __restrict__ h,
                                              const int* __restrict__ idx,
                                              float* __restrict__ h_upd,
                                              float* __restrict__ u_ws){
    int id = blockIdx.x*256 + threadIdx.x;     // exactly MQ*HD
    int n = id >> 7, o = id & 127;
    float r = 1.f/(1.f + expf(-S1[n*256 + o]));
    float u = 1.f/(1.f + expf(-S1[n*256 + 128 + o]));
    float hold = h[(size_t)idx[n]*HD + o];
    h_upd[id] = r * hold;
    u_ws[id] = u;
}

// ---------------- act2: out = (1-u)*h_upd + u*tanh(Sc) ---------------------------
__global__ __launch_bounds__(256) void k_act2(const float* __restrict__ Sc,
                                              const float* __restrict__ h_upd,
                                              const float* __restrict__ u_ws,
                                              float* __restrict__ out){
    int id = blockIdx.x*256 + threadIdx.x;     // exactly MQ*HD
    float c = tanhf(Sc[id]);
    float u = u_ws[id];
    out[id] = (1.f - u)*h_upd[id] + u*c;
}

extern "C" void kernel_launch(void* const* d_in, const int* in_sizes, int n_in,
                              void* d_out, int out_size, void* d_ws, size_t ws_size,
                              hipStream_t stream) {
    (void)in_sizes; (void)n_in; (void)out_size; (void)ws_size;
    const float* x   = (const float*)d_in[0];   // [4096,129]
    const float* h   = (const float*)d_in[1];   // [4096,128]
    const float* q   = (const float*)d_in[2];   // [2048,32]
    const float* adj = (const float*)d_in[3];   // [4096,4096]
    const int*   idx = (const int*)d_in[4];     // [2048]
    const float* Wu  = (const float*)d_in[5];   // [32,257,128]
    const float* bu  = (const float*)d_in[6];   // [32,128]
    const float* Wr  = (const float*)d_in[7];
    const float* br  = (const float*)d_in[8];
    const float* Wc  = (const float*)d_in[9];
    const float* bc  = (const float*)d_in[10];
    float* out = (float*)d_out;

    char* wsb = (char*)d_ws;
    float* cat   = (float*)(wsb + 0);           //  4096*320*4  = 5,242,880
    float* cg    = (float*)(wsb + 5242880);     //  2048*320*4  = 2,621,440
    u16*   P     = (u16*)  (wsb + 7864320);     //  2048*8256*2 = 33,816,576 (reused for P2)
    float* S1    = (float*)(wsb + 41680896);    //  2048*256*4  = 2,097,152
    float* u_ws  = (float*)(wsb + 43778048);    //  2048*128*4  = 1,048,576
    float* h_upd = (float*)(wsb + 44826624);    //  2048*128*4  = 1,048,576
    float* Sc    = (float*)(wsb + 45875200);    //  2048*128*4  = 1,048,576  (end ~46.9 MB)

    k_pack_cat <<<dim3(NN*CATP/256), 256, 0, stream>>>(x, h, cat);
    k_conv_gemm<<<dim3(CATP/64, MQ/32), 256, 0, stream>>>(adj, cat, idx, cg);
    k_build_p1 <<<dim3((KP+255)/256, MQ), 256, 0, stream>>>(q, cg, P);
    // r (cols 0:128, from W_r) and u (cols 128:256, from W_u) in one dispatch
    k_gate_gemm<<<dim3(4, MQ/32), 256, 0, stream>>>(P, Wr, br, Wu, bu, S1, 256);
    k_act1     <<<dim3(MQ*HD/256), 256, 0, stream>>>(S1, h, idx, h_upd, u_ws);
    k_build_p2 <<<dim3((KP+255)/256, MQ), 256, 0, stream>>>(q, x, idx, h_upd, P);
    k_gate_gemm<<<dim3(2, MQ/32), 256, 0, stream>>>(P, Wc, bc, Wc, bc, Sc, 128);
    k_act2     <<<dim3(MQ*HD/256), 256, 0, stream>>>(Sc, h_upd, u_ws, out);
}

// Round 3
// 440.265 us; speedup vs baseline: 2.4757x; 2.4757x over previous
//
#include <hip/hip_runtime.h>
#include <hip/hip_bf16.h>

typedef unsigned short u16;
typedef unsigned int u32;
typedef __attribute__((ext_vector_type(8))) short bf16x8;   // 8 bf16 = 4 VGPR
typedef __attribute__((ext_vector_type(4))) float f32x4;

#define NN 4096
#define MQ 2048
#define QDIM 32
#define IND 257
#define KW 8224      // 32*257
#define KP 8256      // padded to 129*64 (pad rows are zero)
#define HD 128
#define XD 129
#define CATP 320     // padded feature count (5*64)

__device__ __forceinline__ u16 f2bf(float f){
    u32 x = __float_as_uint(f);
    return (u16)((x + 0x7fffu + ((x>>16)&1u)) >> 16);
}

__device__ __forceinline__ void gload16(const void* g, void* l){
    // 64 lanes x 16B -> LDS base + lane*16 (wave-uniform dest, per-lane source)
    __builtin_amdgcn_global_load_lds((const __attribute__((address_space(1))) unsigned int*)g,
                                     (__attribute__((address_space(3))) unsigned int*)l,
                                     16, 0, 0);
}

__device__ __forceinline__ bf16x8 lds_read8(const void* base, int byte_off){
    return *(const bf16x8*)((const char*)base + byte_off);
}

// ---------- W transpose+cvt: WT_ru[256][8256], WT_c[128][8256] (bf16, zero-pad K) ----
__global__ __launch_bounds__(256) void k_cvt_w(const float* __restrict__ Wr,
                                               const float* __restrict__ Wu,
                                               const float* __restrict__ Wc,
                                               u16* __restrict__ WTru,
                                               u16* __restrict__ WTc){
    const int g = blockIdx.y;                 // 0=r, 1=u, 2=c
    const int n = threadIdx.x & 127;          // source column
    const int k0 = blockIdx.x*64 + (threadIdx.x >> 7)*32;
    const float* W = (g==0) ? Wr : (g==1) ? Wu : Wc;
    u16* dst = (g==0) ? (WTru + (size_t)n*KP)
             : (g==1) ? (WTru + (size_t)(128+n)*KP)
                      : (WTc  + (size_t)n*KP);
    alignas(16) u16 buf[32];
    #pragma unroll
    for (int i = 0; i < 32; ++i){
        int k = k0 + i;
        buf[i] = (k < KW) ? f2bf(W[(size_t)k*HD + n]) : (u16)0;
    }
    #pragma unroll
    for (int v = 0; v < 4; ++v)
        *reinterpret_cast<uint4*>(dst + k0 + v*8) = *reinterpret_cast<const uint4*>(&buf[v*8]);
}

// ---------- qb = q @ [br | bu | bc]  (f32, exact bias path) --------------------------
__global__ __launch_bounds__(384) void k_qb(const float* __restrict__ q,
                                            const float* __restrict__ br,
                                            const float* __restrict__ bu,
                                            const float* __restrict__ bc,
                                            float* __restrict__ qb1,
                                            float* __restrict__ qbc){
    const int n = blockIdx.x;
    const int o = threadIdx.x;                // 0..383
    __shared__ float qs[QDIM];
    if (o < QDIM) qs[o] = q[n*QDIM + o];
    __syncthreads();
    const float* B = (o < 128) ? (br + o) : (o < 256) ? (bu + (o-128)) : (bc + (o-256));
    float s = 0.f;
    #pragma unroll
    for (int d = 0; d < QDIM; ++d) s += qs[d] * B[(size_t)d*HD];
    if (o < 256) qb1[(size_t)n*256 + o] = s;
    else         qbc[(size_t)n*HD + (o-256)] = s;
}

// ---------- catT[320][4096] bf16: catT[c][node] = concat(x,h)[node][c] ----------------
__global__ __launch_bounds__(256) void k_pack_catT(const float* __restrict__ x,
                                                   const float* __restrict__ h,
                                                   u16* __restrict__ catT){
    const int t = blockIdx.x*256 + threadIdx.x;   // 0..511
    const int c = blockIdx.y;                      // 0..319
    const int k = t*8;                             // node base
    alignas(16) u16 o[8];
    #pragma unroll
    for (int i = 0; i < 8; ++i){
        int node = k + i;
        float v = (c < XD) ? x[(size_t)node*XD + c]
                : (c < IND) ? h[(size_t)node*HD + (c - XD)] : 0.f;
        o[i] = f2bf(v);
    }
    *reinterpret_cast<uint4*>(catT + (size_t)c*NN + k) = *reinterpret_cast<const uint4*>(o);
}

// ---------- conv MFMA GEMM: cg[2048][320] = adj[idx,:] @ catT^T ----------------------
// BM=BN=BK=64, 256 thr = 4 waves (2x2 of 32x32), f32 acc
__global__ __launch_bounds__(256) void k_conv_mfma(const float* __restrict__ adj,
                                                   const u16* __restrict__ catT,
                                                   const int* __restrict__ idx,
                                                   float* __restrict__ cg){
    __shared__ u16 Asm[64*64];   // [row][k] swizzled
    __shared__ u16 Bsm[64*64];   // [n][k]  swizzled
    __shared__ int rows[64];
    const int tid = threadIdx.x;
    const int wave = tid >> 6, lane = tid & 63;
    const int m0 = blockIdx.y*64, n0 = blockIdx.x*64;
    if (tid < 64) rows[tid] = idx[m0 + tid];
    __syncthreads();

    // A staging (f32 -> bf16 cvt): thread covers row=tid>>2, 16 k at kq=(tid&3)*16
    const int trow = tid >> 2, kq = (tid & 3)*16;
    const float* arow = adj + (size_t)rows[trow]*NN;
    const int r7 = trow & 7;
    char* aw0 = (char*)Asm + trow*128 + (((kq*2)      ) ^ (r7<<4));
    char* aw1 = (char*)Asm + trow*128 + (((kq*2) + 16 ) ^ (r7<<4));

    // B staging via global_load_lds, pre-swizzled source
    const int sw = (((lane&7) ^ (lane>>3)) << 4);
    const char* pB = (const char*)catT + (size_t)(n0 + wave*16 + (lane>>3))*(NN*2) + sw;
    char* lB = (char*)Bsm + wave*2048;

    const int la = lane & 15, lh = lane >> 4;
    const int wr = wave >> 1, wc = wave & 1;
    f32x4 acc[2][2] = {};

    for (int k0 = 0; k0 < NN; k0 += 64){
        // stage B (async)
        gload16(pB + k0*2,                        lB);
        gload16(pB + k0*2 + (size_t)8*(NN*2),     lB + 1024);
        // stage A: load 16 f32, cvt, swizzled ds_write_b128 x2
        alignas(16) u16 tmp[16];
        #pragma unroll
        for (int v = 0; v < 4; ++v){
            float4 f = *reinterpret_cast<const float4*>(arow + k0 + kq + v*4);
            tmp[v*4+0] = f2bf(f.x); tmp[v*4+1] = f2bf(f.y);
            tmp[v*4+2] = f2bf(f.z); tmp[v*4+3] = f2bf(f.w);
        }
        *reinterpret_cast<uint4*>(aw0) = *reinterpret_cast<const uint4*>(&tmp[0]);
        *reinterpret_cast<uint4*>(aw1) = *reinterpret_cast<const uint4*>(&tmp[8]);
        __syncthreads();
        #pragma unroll
        for (int ks = 0; ks < 2; ++ks){
            const int kb = ks*64 + lh*16;
            bf16x8 a0 = lds_read8(Asm, (wr*32 +  0 + la)*128 + (kb ^ ((la&7)<<4)));
            bf16x8 a1 = lds_read8(Asm, (wr*32 + 16 + la)*128 + (kb ^ ((la&7)<<4)));
            bf16x8 b0 = lds_read8(Bsm, (wc*32 +  0 + la)*128 + (kb ^ ((la&7)<<4)));
            bf16x8 b1 = lds_read8(Bsm, (wc*32 + 16 + la)*128 + (kb ^ ((la&7)<<4)));
            acc[0][0] = __builtin_amdgcn_mfma_f32_16x16x32_bf16(a0, b0, acc[0][0], 0, 0, 0);
            acc[0][1] = __builtin_amdgcn_mfma_f32_16x16x32_bf16(a0, b1, acc[0][1], 0, 0, 0);
            acc[1][0] = __builtin_amdgcn_mfma_f32_16x16x32_bf16(a1, b0, acc[1][0], 0, 0, 0);
            acc[1][1] = __builtin_amdgcn_mfma_f32_16x16x32_bf16(a1, b1, acc[1][1], 0, 0, 0);
        }
        __syncthreads();
    }
    #pragma unroll
    for (int fr = 0; fr < 2; ++fr)
        #pragma unroll
        for (int fc = 0; fc < 2; ++fc){
            int m = m0 + wr*32 + fr*16 + lh*4;
            int n = n0 + wc*32 + fc*16 + la;
            #pragma unroll
            for (int j = 0; j < 4; ++j)
                cg[(size_t)(m+j)*CATP + n] = acc[fr][fc][j];
        }
}

// ---------- build P1: P[n][k] = bf16(q[n,k/257] * cg[n,k%257]); K-pad zeros ----------
__global__ __launch_bounds__(256) void k_build_p1(const float* __restrict__ q,
                                                  const float* __restrict__ cg,
                                                  u16* __restrict__ P){
    const int c = blockIdx.x*256 + threadIdx.x;
    if (c >= KP/8) return;
    const int n = blockIdx.y;
    const int k = c*8;
    alignas(16) u16 o[8];
    #pragma unroll
    for (int j = 0; j < 8; ++j){
        int kk = k + j;
        float v = 0.f;
        if (kk < KW){
            int d = kk / IND;
            int i = kk - d*IND;
            v = q[n*QDIM + d] * cg[(size_t)n*CATP + i];
        }
        o[j] = f2bf(v);
    }
    *reinterpret_cast<uint4*>(P + (size_t)n*KP + k) = *reinterpret_cast<const uint4*>(o);
}

// ---------- build P2 from cn = [x[idx[n]], h_upd[n]] ---------------------------------
__global__ __launch_bounds__(256) void k_build_p2(const float* __restrict__ q,
                                                  const float* __restrict__ x,
                                                  const int* __restrict__ idx,
                                                  const float* __restrict__ h_upd,
                                                  u16* __restrict__ P){
    const int c = blockIdx.x*256 + threadIdx.x;
    if (c >= KP/8) return;
    const int n = blockIdx.y;
    const int k = c*8;
    alignas(16) u16 o[8];
    #pragma unroll
    for (int j = 0; j < 8; ++j){
        int kk = k + j;
        float v = 0.f;
        if (kk < KW){
            int d = kk / IND;
            int i = kk - d*IND;
            float f = (i < XD) ? x[(size_t)idx[n]*XD + i] : h_upd[(size_t)n*HD + (i - XD)];
            v = q[n*QDIM + d] * f;
        }
        o[j] = f2bf(v);
    }
    *reinterpret_cast<uint4*>(P + (size_t)n*KP + k) = *reinterpret_cast<const uint4*>(o);
}

// ---------- gate MFMA GEMM: out[2048][N] = P @ WT^T + qb  (K = 8256) -----------------
// BM=BN=BK=64, 4 waves (2x2), both operands via global_load_lds w/ pre-swizzled source
__global__ __launch_bounds__(256) void k_gate_mfma(const u16* __restrict__ P,
                                                   const u16* __restrict__ WT,
                                                   const float* __restrict__ qb,
                                                   float* __restrict__ out, int N){
    __shared__ u16 Asm[64*64];
    __shared__ u16 Bsm[64*64];
    const int tid = threadIdx.x;
    const int wave = tid >> 6, lane = tid & 63;
    const int m0 = blockIdx.y*64, n0 = blockIdx.x*64;

    const int sw = (((lane&7) ^ (lane>>3)) << 4);
    const char* pA = (const char*)P  + (size_t)(m0 + wave*16 + (lane>>3))*(KP*2) + sw;
    const char* pB = (const char*)WT + (size_t)(n0 + wave*16 + (lane>>3))*(KP*2) + sw;
    char* lA = (char*)Asm + wave*2048;
    char* lB = (char*)Bsm + wave*2048;

    const int la = lane & 15, lh = lane >> 4;
    const int wr = wave >> 1, wc = wave & 1;
    f32x4 acc[2][2] = {};

    for (int k0 = 0; k0 < KP; k0 += 64){
        const size_t off = (size_t)k0*2;
        gload16(pA + off,                      lA);
        gload16(pA + off + (size_t)8*(KP*2),   lA + 1024);
        gload16(pB + off,                      lB);
        gload16(pB + off + (size_t)8*(KP*2),   lB + 1024);
        __syncthreads();
        #pragma unroll
        for (int ks = 0; ks < 2; ++ks){
            const int kb = ks*64 + lh*16;
            bf16x8 a0 = lds_read8(Asm, (wr*32 +  0 + la)*128 + (kb ^ ((la&7)<<4)));
            bf16x8 a1 = lds_read8(Asm, (wr*32 + 16 + la)*128 + (kb ^ ((la&7)<<4)));
            bf16x8 b0 = lds_read8(Bsm, (wc*32 +  0 + la)*128 + (kb ^ ((la&7)<<4)));
            bf16x8 b1 = lds_read8(Bsm, (wc*32 + 16 + la)*128 + (kb ^ ((la&7)<<4)));
            acc[0][0] = __builtin_amdgcn_mfma_f32_16x16x32_bf16(a0, b0, acc[0][0], 0, 0, 0);
            acc[0][1] = __builtin_amdgcn_mfma_f32_16x16x32_bf16(a0, b1, acc[0][1], 0, 0, 0);
            acc[1][0] = __builtin_amdgcn_mfma_f32_16x16x32_bf16(a1, b0, acc[1][0], 0, 0, 0);
            acc[1][1] = __builtin_amdgcn_mfma_f32_16x16x32_bf16(a1, b1, acc[1][1], 0, 0, 0);
        }
        __syncthreads();
    }
    #pragma unroll
    for (int fr = 0; fr < 2; ++fr)
        #pragma unroll
        for (int fc = 0; fc < 2; ++fc){
            int m = m0 + wr*32 + fr*16 + lh*4;
            int n = n0 + wc*32 + fc*16 + la;
            #pragma unroll
            for (int j = 0; j < 4; ++j)
                out[(size_t)(m+j)*N + n] = acc[fr][fc][j] + qb[(size_t)(m+j)*N + n];
        }
}

// ---------- act1: r,u = sigmoid; h_upd = r * h[idx]; u_ws = u ------------------------
__global__ __launch_bounds__(256) void k_act1(const float* __restrict__ S1,
                                              const float* __restrict__ h,
                                              const int* __restrict__ idx,
                                              float* __restrict__ h_upd,
                                              float* __restrict__ u_ws){
    int id = blockIdx.x*256 + threadIdx.x;
    int n = id >> 7, o = id & 127;
    float r = 1.f/(1.f + expf(-S1[n*256 + o]));
    float u = 1.f/(1.f + expf(-S1[n*256 + 128 + o]));
    float hold = h[(size_t)idx[n]*HD + o];
    h_upd[id] = r * hold;
    u_ws[id] = u;
}

// ---------- act2: out = (1-u)*h_upd + u*tanh(Sc) -------------------------------------
__global__ __launch_bounds__(256) void k_act2(const float* __restrict__ Sc,
                                              const float* __restrict__ h_upd,
                                              const float* __restrict__ u_ws,
                                              float* __restrict__ out){
    int id = blockIdx.x*256 + threadIdx.x;
    float c = tanhf(Sc[id]);
    float u = u_ws[id];
    out[id] = (1.f - u)*h_upd[id] + u*c;
}

extern "C" void kernel_launch(void* const* d_in, const int* in_sizes, int n_in,
                              void* d_out, int out_size, void* d_ws, size_t ws_size,
                              hipStream_t stream) {
    (void)in_sizes; (void)n_in; (void)out_size; (void)ws_size;
    const float* x   = (const float*)d_in[0];
    const float* h   = (const float*)d_in[1];
    const float* q   = (const float*)d_in[2];
    const float* adj = (const float*)d_in[3];
    const int*   idx = (const int*)d_in[4];
    const float* Wu  = (const float*)d_in[5];
    const float* bu  = (const float*)d_in[6];
    const float* Wr  = (const float*)d_in[7];
    const float* br  = (const float*)d_in[8];
    const float* Wc  = (const float*)d_in[9];
    const float* bc  = (const float*)d_in[10];
    float* out = (float*)d_out;

    char* wsb = (char*)d_ws;
    u16*   catT  = (u16*)  (wsb + 0);            // 320*4096*2   = 2,621,440
    u16*   WTru  = (u16*)  (wsb + 2621440);      // 256*8256*2   = 4,227,072
    u16*   WTc   = (u16*)  (wsb + 6848512);      // 128*8256*2   = 2,113,536
    float* qb1   = (float*)(wsb + 8962048);      // 2048*256*4   = 2,097,152
    float* qbc   = (float*)(wsb + 11059200);     // 2048*128*4   = 1,048,576
    float* cg    = (float*)(wsb + 12107776);     // 2048*320*4   = 2,621,440
    u16*   P     = (u16*)  (wsb + 14729216);     // 2048*8256*2  = 33,816,576  (end 48,545,792)
    float* S1    = (float*)(wsb + 12107776);     // aliases cg   (cg dead after build_p1)
    float* h_upd = (float*)(wsb + 0);            // aliases catT (dead after conv)
    float* u_ws  = (float*)(wsb + 1048576);      // aliases catT upper half
    float* Sc    = (float*)(wsb + 8962048);      // aliases qb1  (dead after gate1)

    k_cvt_w    <<<dim3(KP/64, 3),        256, 0, stream>>>(Wr, Wu, Wc, WTru, WTc);
    k_qb       <<<dim3(MQ),              384, 0, stream>>>(q, br, bu, bc, qb1, qbc);
    k_pack_catT<<<dim3(2, CATP),         256, 0, stream>>>(x, h, catT);
    k_conv_mfma<<<dim3(CATP/64, MQ/64),  256, 0, stream>>>(adj, catT, idx, cg);
    k_build_p1 <<<dim3(5, MQ),           256, 0, stream>>>(q, cg, P);
    k_gate_mfma<<<dim3(4, MQ/64),        256, 0, stream>>>(P, WTru, qb1, S1, 256);
    k_act1     <<<dim3(MQ*HD/256),       256, 0, stream>>>(S1, h, idx, h_upd, u_ws);
    k_build_p2 <<<dim3(5, MQ),           256, 0, stream>>>(q, x, idx, h_upd, P);
    k_gate_mfma<<<dim3(2, MQ/64),        256, 0, stream>>>(P, WTc, qbc, Sc, 128);
    k_act2     <<<dim3(MQ*HD/256),       256, 0, stream>>>(Sc, h_upd, u_ws, out);
}

// Round 4
// 310.838 us; speedup vs baseline: 3.5065x; 1.4164x over previous
//
#include <hip/hip_runtime.h>
#include <hip/hip_bf16.h>

typedef unsigned short u16;
typedef unsigned int u32;
typedef __attribute__((ext_vector_type(8))) short bf16x8;   // 8 bf16 = 4 VGPR
typedef __attribute__((ext_vector_type(4))) float f32x4;

#define NN 4096
#define MQ 2048
#define QDIM 32
#define IND 257
#define KW 8224      // 32*257
#define KP 8256      // padded to 129*64 (pad rows are zero)
#define HD 128
#define XD 129
#define CATP 320     // padded feature count (5*64)

__device__ __forceinline__ u16 f2bf(float f){
    u32 x = __float_as_uint(f);
    return (u16)((x + 0x7fffu + ((x>>16)&1u)) >> 16);
}

__device__ __forceinline__ void gload16(const void* g, void* l){
    __builtin_amdgcn_global_load_lds((const __attribute__((address_space(1))) unsigned int*)g,
                                     (__attribute__((address_space(3))) unsigned int*)l,
                                     16, 0, 0);
}

__device__ __forceinline__ bf16x8 lds_read8(const void* base, int byte_off){
    return *(const bf16x8*)((const char*)base + byte_off);
}

// ---------- W transpose+cvt: WT_ru[256][8256], WT_c[128][8256] (bf16, zero-pad K) ----
__global__ __launch_bounds__(256) void k_cvt_w(const float* __restrict__ Wr,
                                               const float* __restrict__ Wu,
                                               const float* __restrict__ Wc,
                                               u16* __restrict__ WTru,
                                               u16* __restrict__ WTc){
    const int g = blockIdx.y;                 // 0=r, 1=u, 2=c
    const int n = threadIdx.x & 127;          // source column
    const int k0 = blockIdx.x*64 + (threadIdx.x >> 7)*32;
    const float* W = (g==0) ? Wr : (g==1) ? Wu : Wc;
    u16* dst = (g==0) ? (WTru + (size_t)n*KP)
             : (g==1) ? (WTru + (size_t)(128+n)*KP)
                      : (WTc  + (size_t)n*KP);
    alignas(16) u16 buf[32];
    #pragma unroll
    for (int i = 0; i < 32; ++i){
        int k = k0 + i;
        buf[i] = (k < KW) ? f2bf(W[(size_t)k*HD + n]) : (u16)0;
    }
    #pragma unroll
    for (int v = 0; v < 4; ++v)
        *reinterpret_cast<uint4*>(dst + k0 + v*8) = *reinterpret_cast<const uint4*>(&buf[v*8]);
}

// ---------- qb = q @ [br | bu | bc] written INTO the gate accumulators (init) --------
__global__ __launch_bounds__(384) void k_qb(const float* __restrict__ q,
                                            const float* __restrict__ br,
                                            const float* __restrict__ bu,
                                            const float* __restrict__ bc,
                                            float* __restrict__ S1,
                                            float* __restrict__ Sc){
    const int n = blockIdx.x;
    const int o = threadIdx.x;                // 0..383
    __shared__ float qs[QDIM];
    if (o < QDIM) qs[o] = q[n*QDIM + o];
    __syncthreads();
    const float* B = (o < 128) ? (br + o) : (o < 256) ? (bu + (o-128)) : (bc + (o-256));
    float s = 0.f;
    #pragma unroll
    for (int d = 0; d < QDIM; ++d) s += qs[d] * B[(size_t)d*HD];
    if (o < 256) S1[(size_t)n*256 + o] = s;
    else         Sc[(size_t)n*HD + (o-256)] = s;
}

// ---------- zero cg (atomic accumulator init) ----------------------------------------
__global__ __launch_bounds__(256) void k_zero(float* __restrict__ p){
    reinterpret_cast<float4*>(p)[blockIdx.x*256 + threadIdx.x] = float4{0.f,0.f,0.f,0.f};
}

// ---------- catT[320][4096] bf16: catT[c][node] = concat(x,h)[node][c] ----------------
__global__ __launch_bounds__(256) void k_pack_catT(const float* __restrict__ x,
                                                   const float* __restrict__ h,
                                                   u16* __restrict__ catT){
    const int t = blockIdx.x*256 + threadIdx.x;   // 0..511
    const int c = blockIdx.y;                      // 0..319
    const int k = t*8;                             // node base
    alignas(16) u16 o[8];
    #pragma unroll
    for (int i = 0; i < 8; ++i){
        int node = k + i;
        float v = (c < XD) ? x[(size_t)node*XD + c]
                : (c < IND) ? h[(size_t)node*HD + (c - XD)] : 0.f;
        o[i] = f2bf(v);
    }
    *reinterpret_cast<uint4*>(catT + (size_t)c*NN + k) = *reinterpret_cast<const uint4*>(o);
}

// ---------- conv MFMA GEMM (split-K=8): cg += adj[idx,:] @ catT^T --------------------
__global__ __launch_bounds__(256) void k_conv_mfma(const float* __restrict__ adj,
                                                   const u16* __restrict__ catT,
                                                   const int* __restrict__ idx,
                                                   float* __restrict__ cg){
    __shared__ u16 Asm[64*64];
    __shared__ u16 Bsm[64*64];
    __shared__ int rows[64];
    const int tid = threadIdx.x;
    const int wave = tid >> 6, lane = tid & 63;
    const int m0 = blockIdx.y*64, n0 = blockIdx.x*64;
    const int s = blockIdx.z;                      // split: k range [s*512, s*512+512)
    if (tid < 64) rows[tid] = idx[m0 + tid];
    __syncthreads();

    const int trow = tid >> 2, kq = (tid & 3)*16;
    const float* arow = adj + (size_t)rows[trow]*NN;
    const int r7 = trow & 7;
    char* aw0 = (char*)Asm + trow*128 + (((kq*2)      ) ^ (r7<<4));
    char* aw1 = (char*)Asm + trow*128 + (((kq*2) + 16 ) ^ (r7<<4));

    const int sw = (((lane&7) ^ (lane>>3)) << 4);
    const char* pB = (const char*)catT + (size_t)(n0 + wave*16 + (lane>>3))*(NN*2) + sw;
    char* lB = (char*)Bsm + wave*2048;

    const int la = lane & 15, lh = lane >> 4;
    const int wr = wave >> 1, wc = wave & 1;
    f32x4 acc[2][2] = {};

    for (int k0 = s*512; k0 < s*512 + 512; k0 += 64){
        gload16(pB + (size_t)k0*2,                    lB);
        gload16(pB + (size_t)k0*2 + (size_t)8*(NN*2), lB + 1024);
        alignas(16) u16 tmp[16];
        #pragma unroll
        for (int v = 0; v < 4; ++v){
            float4 f = *reinterpret_cast<const float4*>(arow + k0 + kq + v*4);
            tmp[v*4+0] = f2bf(f.x); tmp[v*4+1] = f2bf(f.y);
            tmp[v*4+2] = f2bf(f.z); tmp[v*4+3] = f2bf(f.w);
        }
        *reinterpret_cast<uint4*>(aw0) = *reinterpret_cast<const uint4*>(&tmp[0]);
        *reinterpret_cast<uint4*>(aw1) = *reinterpret_cast<const uint4*>(&tmp[8]);
        __syncthreads();
        #pragma unroll
        for (int ks = 0; ks < 2; ++ks){
            const int kb = ks*64 + lh*16;
            bf16x8 a0 = lds_read8(Asm, (wr*32 +  0 + la)*128 + (kb ^ ((la&7)<<4)));
            bf16x8 a1 = lds_read8(Asm, (wr*32 + 16 + la)*128 + (kb ^ ((la&7)<<4)));
            bf16x8 b0 = lds_read8(Bsm, (wc*32 +  0 + la)*128 + (kb ^ ((la&7)<<4)));
            bf16x8 b1 = lds_read8(Bsm, (wc*32 + 16 + la)*128 + (kb ^ ((la&7)<<4)));
            acc[0][0] = __builtin_amdgcn_mfma_f32_16x16x32_bf16(a0, b0, acc[0][0], 0, 0, 0);
            acc[0][1] = __builtin_amdgcn_mfma_f32_16x16x32_bf16(a0, b1, acc[0][1], 0, 0, 0);
            acc[1][0] = __builtin_amdgcn_mfma_f32_16x16x32_bf16(a1, b0, acc[1][0], 0, 0, 0);
            acc[1][1] = __builtin_amdgcn_mfma_f32_16x16x32_bf16(a1, b1, acc[1][1], 0, 0, 0);
        }
        __syncthreads();
    }
    #pragma unroll
    for (int fr = 0; fr < 2; ++fr)
        #pragma unroll
        for (int fc = 0; fc < 2; ++fc){
            int m = m0 + wr*32 + fr*16 + lh*4;
            int n = n0 + wc*32 + fc*16 + la;
            #pragma unroll
            for (int j = 0; j < 4; ++j)
                atomicAdd(&cg[(size_t)(m+j)*CATP + n], acc[fr][fc][j]);
        }
}

// ---------- build P1: P[n][k] = bf16(q[n,k/257] * cg[n,k%257]); K-pad zeros ----------
__global__ __launch_bounds__(256) void k_build_p1(const float* __restrict__ q,
                                                  const float* __restrict__ cg,
                                                  u16* __restrict__ P){
    const int c = blockIdx.x*256 + threadIdx.x;
    if (c >= KP/8) return;
    const int n = blockIdx.y;
    const int k = c*8;
    alignas(16) u16 o[8];
    #pragma unroll
    for (int j = 0; j < 8; ++j){
        int kk = k + j;
        float v = 0.f;
        if (kk < KW){
            int d = kk / IND;
            int i = kk - d*IND;
            v = q[n*QDIM + d] * cg[(size_t)n*CATP + i];
        }
        o[j] = f2bf(v);
    }
    *reinterpret_cast<uint4*>(P + (size_t)n*KP + k) = *reinterpret_cast<const uint4*>(o);
}

// ---------- build P2 from cn = [x[idx[n]], h_upd[n]] ---------------------------------
__global__ __launch_bounds__(256) void k_build_p2(const float* __restrict__ q,
                                                  const float* __restrict__ x,
                                                  const int* __restrict__ idx,
                                                  const float* __restrict__ h_upd,
                                                  u16* __restrict__ P){
    const int c = blockIdx.x*256 + threadIdx.x;
    if (c >= KP/8) return;
    const int n = blockIdx.y;
    const int k = c*8;
    alignas(16) u16 o[8];
    #pragma unroll
    for (int j = 0; j < 8; ++j){
        int kk = k + j;
        float v = 0.f;
        if (kk < KW){
            int d = kk / IND;
            int i = kk - d*IND;
            float f = (i < XD) ? x[(size_t)idx[n]*XD + i] : h_upd[(size_t)n*HD + (i - XD)];
            v = q[n*QDIM + d] * f;
        }
        o[j] = f2bf(v);
    }
    *reinterpret_cast<uint4*>(P + (size_t)n*KP + k) = *reinterpret_cast<const uint4*>(o);
}

// ---------- gate MFMA GEMM (split-K=8): S += P @ WT^T  (K = 8256 = 129 steps) --------
__global__ __launch_bounds__(256) void k_gate_mfma(const u16* __restrict__ P,
                                                   const u16* __restrict__ WT,
                                                   float* __restrict__ S, int N){
    __shared__ u16 Asm[64*64];
    __shared__ u16 Bsm[64*64];
    const int tid = threadIdx.x;
    const int wave = tid >> 6, lane = tid & 63;
    const int m0 = blockIdx.y*64, n0 = blockIdx.x*64;
    const int s = blockIdx.z;
    const int ts_begin = s*16, ts_end = (s == 7) ? 129 : s*16 + 16;

    const int sw = (((lane&7) ^ (lane>>3)) << 4);
    const char* pA = (const char*)P  + (size_t)(m0 + wave*16 + (lane>>3))*(KP*2) + sw;
    const char* pB = (const char*)WT + (size_t)(n0 + wave*16 + (lane>>3))*(KP*2) + sw;
    char* lA = (char*)Asm + wave*2048;
    char* lB = (char*)Bsm + wave*2048;

    const int la = lane & 15, lh = lane >> 4;
    const int wr = wave >> 1, wc = wave & 1;
    f32x4 acc[2][2] = {};

    for (int t = ts_begin; t < ts_end; ++t){
        const size_t off = (size_t)t*128;      // t*64 elems * 2B
        gload16(pA + off,                      lA);
        gload16(pA + off + (size_t)8*(KP*2),   lA + 1024);
        gload16(pB + off,                      lB);
        gload16(pB + off + (size_t)8*(KP*2),   lB + 1024);
        __syncthreads();
        #pragma unroll
        for (int ks = 0; ks < 2; ++ks){
            const int kb = ks*64 + lh*16;
            bf16x8 a0 = lds_read8(Asm, (wr*32 +  0 + la)*128 + (kb ^ ((la&7)<<4)));
            bf16x8 a1 = lds_read8(Asm, (wr*32 + 16 + la)*128 + (kb ^ ((la&7)<<4)));
            bf16x8 b0 = lds_read8(Bsm, (wc*32 +  0 + la)*128 + (kb ^ ((la&7)<<4)));
            bf16x8 b1 = lds_read8(Bsm, (wc*32 + 16 + la)*128 + (kb ^ ((la&7)<<4)));
            acc[0][0] = __builtin_amdgcn_mfma_f32_16x16x32_bf16(a0, b0, acc[0][0], 0, 0, 0);
            acc[0][1] = __builtin_amdgcn_mfma_f32_16x16x32_bf16(a0, b1, acc[0][1], 0, 0, 0);
            acc[1][0] = __builtin_amdgcn_mfma_f32_16x16x32_bf16(a1, b0, acc[1][0], 0, 0, 0);
            acc[1][1] = __builtin_amdgcn_mfma_f32_16x16x32_bf16(a1, b1, acc[1][1], 0, 0, 0);
        }
        __syncthreads();
    }
    #pragma unroll
    for (int fr = 0; fr < 2; ++fr)
        #pragma unroll
        for (int fc = 0; fc < 2; ++fc){
            int m = m0 + wr*32 + fr*16 + lh*4;
            int n = n0 + wc*32 + fc*16 + la;
            #pragma unroll
            for (int j = 0; j < 4; ++j)
                atomicAdd(&S[(size_t)(m+j)*N + n], acc[fr][fc][j]);
        }
}

// ---------- act1: r,u = sigmoid; h_upd = r * h[idx]; u_ws = u ------------------------
__global__ __launch_bounds__(256) void k_act1(const float* __restrict__ S1,
                                              const float* __restrict__ h,
                                              const int* __restrict__ idx,
                                              float* __restrict__ h_upd,
                                              float* __restrict__ u_ws){
    int id = blockIdx.x*256 + threadIdx.x;
    int n = id >> 7, o = id & 127;
    float r = 1.f/(1.f + expf(-S1[n*256 + o]));
    float u = 1.f/(1.f + expf(-S1[n*256 + 128 + o]));
    float hold = h[(size_t)idx[n]*HD + o];
    h_upd[id] = r * hold;
    u_ws[id] = u;
}

// ---------- act2: out = (1-u)*h_upd + u*tanh(Sc) -------------------------------------
__global__ __launch_bounds__(256) void k_act2(const float* __restrict__ Sc,
                                              const float* __restrict__ h_upd,
                                              const float* __restrict__ u_ws,
                                              float* __restrict__ out){
    int id = blockIdx.x*256 + threadIdx.x;
    float c = tanhf(Sc[id]);
    float u = u_ws[id];
    out[id] = (1.f - u)*h_upd[id] + u*c;
}

extern "C" void kernel_launch(void* const* d_in, const int* in_sizes, int n_in,
                              void* d_out, int out_size, void* d_ws, size_t ws_size,
                              hipStream_t stream) {
    (void)in_sizes; (void)n_in; (void)out_size; (void)ws_size;
    const float* x   = (const float*)d_in[0];
    const float* h   = (const float*)d_in[1];
    const float* q   = (const float*)d_in[2];
    const float* adj = (const float*)d_in[3];
    const int*   idx = (const int*)d_in[4];
    const float* Wu  = (const float*)d_in[5];
    const float* bu  = (const float*)d_in[6];
    const float* Wr  = (const float*)d_in[7];
    const float* br  = (const float*)d_in[8];
    const float* Wc  = (const float*)d_in[9];
    const float* bc  = (const float*)d_in[10];
    float* out = (float*)d_out;

    char* wsb = (char*)d_ws;
    u16*   catT  = (u16*)  (wsb + 0);            // 320*4096*2   = 2,621,440
    u16*   WTru  = (u16*)  (wsb + 2621440);      // 256*8256*2   = 4,227,072
    u16*   WTc   = (u16*)  (wsb + 6848512);      // 128*8256*2   = 2,113,536
    float* S1    = (float*)(wsb + 8962048);      // 2048*256*4   = 2,097,152 (qb1-init + gate1 atomics)
    float* Sc    = (float*)(wsb + 11059200);     // 2048*128*4   = 1,048,576 (qbc-init + gate2 atomics)
    float* cg    = (float*)(wsb + 12107776);     // 2048*320*4   = 2,621,440 (zeroed + conv atomics)
    u16*   P     = (u16*)  (wsb + 14729216);     // 2048*8256*2  = 33,816,576  (end 48,545,792)
    float* h_upd = (float*)(wsb + 0);            // aliases catT (dead after conv)
    float* u_ws  = (float*)(wsb + 1048576);      // aliases catT upper half

    k_cvt_w    <<<dim3(KP/64, 3),          256, 0, stream>>>(Wr, Wu, Wc, WTru, WTc);
    k_qb       <<<dim3(MQ),                384, 0, stream>>>(q, br, bu, bc, S1, Sc);
    k_pack_catT<<<dim3(2, CATP),           256, 0, stream>>>(x, h, catT);
    k_zero     <<<dim3(MQ*CATP/4/256),     256, 0, stream>>>(cg);
    k_conv_mfma<<<dim3(CATP/64, MQ/64, 8), 256, 0, stream>>>(adj, catT, idx, cg);
    k_build_p1 <<<dim3(5, MQ),             256, 0, stream>>>(q, cg, P);
    k_gate_mfma<<<dim3(4, MQ/64, 8),       256, 0, stream>>>(P, WTru, S1, 256);
    k_act1     <<<dim3(MQ*HD/256),         256, 0, stream>>>(S1, h, idx, h_upd, u_ws);
    k_build_p2 <<<dim3(5, MQ),             256, 0, stream>>>(q, x, idx, h_upd, P);
    k_gate_mfma<<<dim3(2, MQ/64, 8),       256, 0, stream>>>(P, WTc, Sc, 128);
    k_act2     <<<dim3(MQ*HD/256),         256, 0, stream>>>(Sc, h_upd, u_ws, out);
}

// Round 5
// 222.494 us; speedup vs baseline: 4.8988x; 1.3971x over previous
//
#include <hip/hip_runtime.h>
#include <hip/hip_bf16.h>

typedef unsigned short u16;
typedef unsigned int u32;
typedef __attribute__((ext_vector_type(8))) short bf16x8;   // 8 bf16 = 4 VGPR
typedef __attribute__((ext_vector_type(4))) float f32x4;

#define NN 4096
#define MQ 2048
#define QDIM 32
#define IND 257
#define NSTEP 258          // i = 0..257; i==257 is the bias step (feat = 1.0, W row = b)
#define K2 (NSTEP*32)      // 8256 = WT2 row length (k' = i*32 + d)
#define HD 128
#define XD 129
#define CATP 320           // padded feature stride

__device__ __forceinline__ u16 f2bf(float f){
    u32 x = __float_as_uint(f);
    return (u16)((x + 0x7fffu + ((x>>16)&1u)) >> 16);
}

__device__ __forceinline__ void gload16(const void* g, void* l){
    __builtin_amdgcn_global_load_lds((const __attribute__((address_space(1))) unsigned int*)g,
                                     (__attribute__((address_space(3))) unsigned int*)l,
                                     16, 0, 0);
}

__device__ __forceinline__ bf16x8 lds_read8(const void* base, int byte_off){
    return *(const bf16x8*)((const char*)base + byte_off);
}

// a_frag = bf16(q8[j] * f), j = 0..7  (RNE via cvt_pk)
__device__ __forceinline__ bf16x8 mk_afrag(const float* q8, float f){
    union { bf16x8 v; __hip_bfloat162 h[4]; } u;
    #pragma unroll
    for (int p = 0; p < 4; ++p){
        float2 t; t.x = q8[2*p]*f; t.y = q8[2*p+1]*f;
        u.h[p] = __float22bfloat162_rn(t);
    }
    return u.v;
}

// ---------- W -> WT2 [o][i*32+d] bf16; i==257 row comes from bias b ------------------
// grid (NSTEP, 3): g=0 Wr->WT2ru rows 0..127, g=1 Wu->rows 128..255, g=2 Wc->WT2c
__global__ __launch_bounds__(128) void k_cvt_w2(const float* __restrict__ Wr,
                                                const float* __restrict__ Wu,
                                                const float* __restrict__ Wc,
                                                const float* __restrict__ br,
                                                const float* __restrict__ bu,
                                                const float* __restrict__ bc,
                                                u16* __restrict__ WT2ru,
                                                u16* __restrict__ WT2c){
    const int i = blockIdx.x, g = blockIdx.y, o = threadIdx.x;
    const float* W = (g==0)?Wr:(g==1)?Wu:Wc;
    const float* B = (g==0)?br:(g==1)?bu:bc;
    u16* dst = (g==0)? WT2ru + (size_t)o*K2
             : (g==1)? WT2ru + (size_t)(128+o)*K2
                     : WT2c  + (size_t)o*K2;
    alignas(16) u16 buf[32];
    if (i < IND){
        #pragma unroll
        for (int d = 0; d < 32; ++d) buf[d] = f2bf(W[((size_t)d*IND + i)*HD + o]);
    } else {
        #pragma unroll
        for (int d = 0; d < 32; ++d) buf[d] = f2bf(B[(size_t)d*HD + o]);
    }
    #pragma unroll
    for (int v = 0; v < 4; ++v)
        *reinterpret_cast<uint4*>(dst + i*32 + v*8) = *reinterpret_cast<const uint4*>(&buf[v*8]);
}

// ---------- zero the atomic accumulators (cg|S1|Sc contiguous) -----------------------
__global__ __launch_bounds__(256) void k_zero(float* __restrict__ p){
    reinterpret_cast<float4*>(p)[blockIdx.x*256 + threadIdx.x] = float4{0.f,0.f,0.f,0.f};
}

// ---------- catT[320][4096] bf16 ------------------------------------------------------
__global__ __launch_bounds__(256) void k_pack_catT(const float* __restrict__ x,
                                                   const float* __restrict__ h,
                                                   u16* __restrict__ catT){
    const int t = blockIdx.x*256 + threadIdx.x;
    const int c = blockIdx.y;
    const int k = t*8;
    alignas(16) u16 o[8];
    #pragma unroll
    for (int i = 0; i < 8; ++i){
        int node = k + i;
        float v = (c < XD) ? x[(size_t)node*XD + c]
                : (c < IND) ? h[(size_t)node*HD + (c - XD)] : 0.f;
        o[i] = f2bf(v);
    }
    *reinterpret_cast<uint4*>(catT + (size_t)c*NN + k) = *reinterpret_cast<const uint4*>(o);
}

// ---------- conv MFMA GEMM (split-K=8): cg += adj[idx,:] @ catT^T --------------------
__global__ __launch_bounds__(256) void k_conv_mfma(const float* __restrict__ adj,
                                                   const u16* __restrict__ catT,
                                                   const int* __restrict__ idx,
                                                   float* __restrict__ cg){
    __shared__ u16 Asm[64*64];
    __shared__ u16 Bsm[64*64];
    __shared__ int rows[64];
    const int tid = threadIdx.x;
    const int wave = tid >> 6, lane = tid & 63;
    const int m0 = blockIdx.y*64, n0 = blockIdx.x*64;
    const int s = blockIdx.z;
    if (tid < 64) rows[tid] = idx[m0 + tid];
    __syncthreads();

    const int trow = tid >> 2, kq = (tid & 3)*16;
    const float* arow = adj + (size_t)rows[trow]*NN;
    const int r7 = trow & 7;
    char* aw0 = (char*)Asm + trow*128 + (((kq*2)      ) ^ (r7<<4));
    char* aw1 = (char*)Asm + trow*128 + (((kq*2) + 16 ) ^ (r7<<4));

    const int sw = (((lane&7) ^ (lane>>3)) << 4);
    const char* pB = (const char*)catT + (size_t)(n0 + wave*16 + (lane>>3))*(NN*2) + sw;
    char* lB = (char*)Bsm + wave*2048;

    const int la = lane & 15, lh = lane >> 4;
    const int wr = wave >> 1, wc = wave & 1;
    f32x4 acc[2][2] = {};

    for (int k0 = s*512; k0 < s*512 + 512; k0 += 64){
        gload16(pB + (size_t)k0*2,                    lB);
        gload16(pB + (size_t)k0*2 + (size_t)8*(NN*2), lB + 1024);
        alignas(16) u16 tmp[16];
        #pragma unroll
        for (int v = 0; v < 4; ++v){
            float4 f = *reinterpret_cast<const float4*>(arow + k0 + kq + v*4);
            tmp[v*4+0] = f2bf(f.x); tmp[v*4+1] = f2bf(f.y);
            tmp[v*4+2] = f2bf(f.z); tmp[v*4+3] = f2bf(f.w);
        }
        *reinterpret_cast<uint4*>(aw0) = *reinterpret_cast<const uint4*>(&tmp[0]);
        *reinterpret_cast<uint4*>(aw1) = *reinterpret_cast<const uint4*>(&tmp[8]);
        __syncthreads();
        #pragma unroll
        for (int ks = 0; ks < 2; ++ks){
            const int kb = ks*64 + lh*16;
            bf16x8 a0 = lds_read8(Asm, (wr*32 +  0 + la)*128 + (kb ^ ((la&7)<<4)));
            bf16x8 a1 = lds_read8(Asm, (wr*32 + 16 + la)*128 + (kb ^ ((la&7)<<4)));
            bf16x8 b0 = lds_read8(Bsm, (wc*32 +  0 + la)*128 + (kb ^ ((la&7)<<4)));
            bf16x8 b1 = lds_read8(Bsm, (wc*32 + 16 + la)*128 + (kb ^ ((la&7)<<4)));
            acc[0][0] = __builtin_amdgcn_mfma_f32_16x16x32_bf16(a0, b0, acc[0][0], 0, 0, 0);
            acc[0][1] = __builtin_amdgcn_mfma_f32_16x16x32_bf16(a0, b1, acc[0][1], 0, 0, 0);
            acc[1][0] = __builtin_amdgcn_mfma_f32_16x16x32_bf16(a1, b0, acc[1][0], 0, 0, 0);
            acc[1][1] = __builtin_amdgcn_mfma_f32_16x16x32_bf16(a1, b1, acc[1][1], 0, 0, 0);
        }
        __syncthreads();
    }
    #pragma unroll
    for (int fr = 0; fr < 2; ++fr)
        #pragma unroll
        for (int fc = 0; fc < 2; ++fc){
            int m = m0 + wr*32 + fr*16 + lh*4;
            int n = n0 + wc*32 + fc*16 + la;
            #pragma unroll
            for (int j = 0; j < 4; ++j)
                atomicAdd(&cg[(size_t)(m+j)*CATP + n], acc[fr][fc][j]);
        }
}

// ---------- fused gate GEMM: S += (q ⊗ feat) @ WT2^T, A built on the fly -------------
// K-step = one feature i (K=32 over d). feat[row][257] := 1.0 (bias step).
// grid (N/64, 32, 8), 256 thr = 4 waves (2x2). Atomic accumulate into S.
__global__ __launch_bounds__(256) void k_gate_fused(const float* __restrict__ feat,
                                                    const float* __restrict__ q,
                                                    const u16* __restrict__ WT2,
                                                    float* __restrict__ S, int N){
    __shared__ float featLds[33*64];
    __shared__ u16 Bsm[64*32];     // per step: 64 cols x 32 k, 64B per col-row, chunk-swizzled
    const int tid = threadIdx.x;
    const int wave = tid >> 6, lane = tid & 63;
    const int la = lane & 15, lh = lane >> 4;
    const int m0 = blockIdx.y*64, n0 = blockIdx.x*64;
    const int z = blockIdx.z;
    const int i0 = z*32 + (z < 2 ? z : 2);
    const int cnt = (z < 2) ? 33 : 32;

    // fill featLds[il][row] = feat[m0+row][i0+il], inject 1.0 at i==257
    {
        const int row = tid >> 2, iq = tid & 3;
        #pragma unroll
        for (int j = 0; j < 9; ++j){
            int il = j*4 + iq;
            if (il < cnt){
                int gi = i0 + il;
                featLds[il*64 + row] = (gi == IND) ? 1.0f
                                     : feat[(size_t)(m0 + row)*CATP + gi];
            }
        }
    }
    // q fragments (once): q8[j] = q[row][lh*8+j]
    const int wr = wave >> 1, wc = wave & 1;
    const int r0l = wr*32 + la, r1l = r0l + 16;
    const float* q0p = q + (size_t)(m0 + r0l)*QDIM + lh*8;
    const float* q1p = q + (size_t)(m0 + r1l)*QDIM + lh*8;
    float q80[8], q81[8];
    *reinterpret_cast<float4*>(&q80[0]) = *reinterpret_cast<const float4*>(q0p);
    *reinterpret_cast<float4*>(&q80[4]) = *reinterpret_cast<const float4*>(q0p + 4);
    *reinterpret_cast<float4*>(&q81[0]) = *reinterpret_cast<const float4*>(q1p);
    *reinterpret_cast<float4*>(&q81[4]) = *reinterpret_cast<const float4*>(q1p + 4);

    // B staging: dest (col cc, slot lane&3) holds k-chunk (lane&3)^((cc>>1)&3)
    const int cc = tid >> 2;
    const int jj = (lane & 3) ^ ((cc >> 1) & 3);
    const u16* pB = WT2 + (size_t)(n0 + cc)*K2 + jj*8;
    char* lB = (char*)Bsm + wave*1024;

    const int col0 = wc*32 + la, col1 = col0 + 16;
    const int b0off = col0*64 + ((lh ^ ((col0>>1)&3)) << 4);
    const int b1off = col1*64 + ((lh ^ ((col1>>1)&3)) << 4);

    f32x4 acc[2][2] = {};
    __syncthreads();                      // featLds ready

    for (int s = 0; s < cnt; ++s){
        gload16(pB + (size_t)(i0 + s)*32, lB);
        __syncthreads();                  // B tile visible (vmcnt drained at barrier)
        float f0 = featLds[s*64 + r0l];
        float f1 = featLds[s*64 + r1l];
        bf16x8 a0 = mk_afrag(q80, f0);
        bf16x8 a1 = mk_afrag(q81, f1);
        bf16x8 b0 = lds_read8(Bsm, b0off);
        bf16x8 b1 = lds_read8(Bsm, b1off);
        acc[0][0] = __builtin_amdgcn_mfma_f32_16x16x32_bf16(a0, b0, acc[0][0], 0, 0, 0);
        acc[0][1] = __builtin_amdgcn_mfma_f32_16x16x32_bf16(a0, b1, acc[0][1], 0, 0, 0);
        acc[1][0] = __builtin_amdgcn_mfma_f32_16x16x32_bf16(a1, b0, acc[1][0], 0, 0, 0);
        acc[1][1] = __builtin_amdgcn_mfma_f32_16x16x32_bf16(a1, b1, acc[1][1], 0, 0, 0);
        __syncthreads();                  // before overwriting Bsm
    }
    #pragma unroll
    for (int fr = 0; fr < 2; ++fr)
        #pragma unroll
        for (int fc = 0; fc < 2; ++fc){
            int m = m0 + wr*32 + fr*16 + lh*4;
            int n = n0 + wc*32 + fc*16 + la;
            #pragma unroll
            for (int j = 0; j < 4; ++j)
                atomicAdd(&S[(size_t)(m+j)*N + n], acc[fr][fc][j]);
        }
}

// ---------- act1: r,u = sigmoid(S1); featf2 = [x[idx], r*h[idx]]; u_ws = u -----------
__global__ __launch_bounds__(256) void k_act1(const float* __restrict__ S1,
                                              const float* __restrict__ h,
                                              const float* __restrict__ x,
                                              const int* __restrict__ idx,
                                              float* __restrict__ featf2,
                                              float* __restrict__ u_ws){
    const int n = blockIdx.x, t = threadIdx.x;
    const int row = idx[n];
    if (t < HD){
        float rr = 1.f/(1.f + expf(-S1[(size_t)n*256 + t]));
        float uu = 1.f/(1.f + expf(-S1[(size_t)n*256 + 128 + t]));
        featf2[(size_t)n*CATP + XD + t] = rr * h[(size_t)row*HD + t];
        u_ws[(size_t)n*HD + t] = uu;
    }
    if (t < XD) featf2[(size_t)n*CATP + t] = x[(size_t)row*XD + t];
}

// ---------- act2: out = (1-u)*h_upd + u*tanh(Sc); h_upd lives in featf2 --------------
__global__ __launch_bounds__(256) void k_act2(const float* __restrict__ Sc,
                                              const float* __restrict__ featf2,
                                              const float* __restrict__ u_ws,
                                              float* __restrict__ out){
    int id = blockIdx.x*256 + threadIdx.x;
    int n = id >> 7, o = id & 127;
    float hupd = featf2[(size_t)n*CATP + XD + o];
    float uu = u_ws[id];
    out[id] = (1.f - uu)*hupd + uu*tanhf(Sc[id]);
}

extern "C" void kernel_launch(void* const* d_in, const int* in_sizes, int n_in,
                              void* d_out, int out_size, void* d_ws, size_t ws_size,
                              hipStream_t stream) {
    (void)in_sizes; (void)n_in; (void)out_size; (void)ws_size;
    const float* x   = (const float*)d_in[0];
    const float* h   = (const float*)d_in[1];
    const float* q   = (const float*)d_in[2];
    const float* adj = (const float*)d_in[3];
    const int*   idx = (const int*)d_in[4];
    const float* Wu  = (const float*)d_in[5];
    const float* bu  = (const float*)d_in[6];
    const float* Wr  = (const float*)d_in[7];
    const float* br  = (const float*)d_in[8];
    const float* Wc  = (const float*)d_in[9];
    const float* bc  = (const float*)d_in[10];
    float* out = (float*)d_out;

    char* wsb = (char*)d_ws;
    u16*   catT   = (u16*)  (wsb + 0);           // 320*4096*2  = 2,621,440
    u16*   WT2ru  = (u16*)  (wsb + 2621440);     // 256*8256*2  = 4,227,072
    u16*   WT2c   = (u16*)  (wsb + 6848512);     // 128*8256*2  = 2,113,536
    float* cg     = (float*)(wsb + 8962048);     // 2048*320*4  = 2,621,440  ┐
    float* S1     = (float*)(wsb + 11583488);    // 2048*256*4  = 2,097,152  ├ zeroed together
    float* Sc     = (float*)(wsb + 13680640);    // 2048*128*4  = 1,048,576  ┘
    float* featf2 = (float*)(wsb + 14729216);    // 2048*320*4  = 2,621,440
    float* u_ws   = (float*)(wsb + 17350656);    // 2048*128*4  = 1,048,576  (end ~18.4 MB)

    k_cvt_w2    <<<dim3(NSTEP, 3),          128, 0, stream>>>(Wr, Wu, Wc, br, bu, bc, WT2ru, WT2c);
    k_zero      <<<dim3(1408),              256, 0, stream>>>(cg);   // cg|S1|Sc = 5,767,168 B
    k_pack_catT <<<dim3(2, CATP),           256, 0, stream>>>(x, h, catT);
    k_conv_mfma <<<dim3(CATP/64, MQ/64, 8), 256, 0, stream>>>(adj, catT, idx, cg);
    k_gate_fused<<<dim3(4, MQ/64, 8),       256, 0, stream>>>(cg, q, WT2ru, S1, 256);
    k_act1      <<<dim3(MQ),                256, 0, stream>>>(S1, h, x, idx, featf2, u_ws);
    k_gate_fused<<<dim3(2, MQ/64, 8),       256, 0, stream>>>(featf2, q, WT2c, Sc, 128);
    k_act2      <<<dim3(MQ*HD/256),         256, 0, stream>>>(Sc, featf2, u_ws, out);
}

// Round 6
// 210.205 us; speedup vs baseline: 5.1852x; 1.0585x over previous
//
#include <hip/hip_runtime.h>
#include <hip/hip_bf16.h>

typedef unsigned short u16;
typedef unsigned int u32;
typedef __attribute__((ext_vector_type(8))) short bf16x8;   // 8 bf16 = 4 VGPR
typedef __attribute__((ext_vector_type(4))) float f32x4;

#define NN 4096
#define MQ 2048
#define QDIM 32
#define IND 257
#define NSTEP 258          // i = 0..257; i==257 is the bias step (feat = 1.0, W row = b)
#define K2 (NSTEP*32)      // 8256 = WT2 row length (k' = i*32 + d)
#define HD 128
#define XD 129
#define CATP 320           // padded feature stride

__device__ __forceinline__ u16 f2bf(float f){
    u32 x = __float_as_uint(f);
    return (u16)((x + 0x7fffu + ((x>>16)&1u)) >> 16);
}

__device__ __forceinline__ void gload16(const void* g, void* l){
    __builtin_amdgcn_global_load_lds((const __attribute__((address_space(1))) unsigned int*)g,
                                     (__attribute__((address_space(3))) unsigned int*)l,
                                     16, 0, 0);
}

__device__ __forceinline__ bf16x8 lds_read8(const void* base, int byte_off){
    return *(const bf16x8*)((const char*)base + byte_off);
}

// a_frag = bf16(q8[j] * f), j = 0..7
__device__ __forceinline__ bf16x8 mk_afrag(const float* q8, float f){
    union { bf16x8 v; __hip_bfloat162 h[4]; } u;
    #pragma unroll
    for (int p = 0; p < 4; ++p){
        float2 t; t.x = q8[2*p]*f; t.y = q8[2*p+1]*f;
        u.h[p] = __float22bfloat162_rn(t);
    }
    return u.v;
}

// ---------- W -> WT2 [o][i*32+d] bf16; i==257 row comes from bias b ------------------
__global__ __launch_bounds__(128) void k_cvt_w2(const float* __restrict__ Wr,
                                                const float* __restrict__ Wu,
                                                const float* __restrict__ Wc,
                                                const float* __restrict__ br,
                                                const float* __restrict__ bu,
                                                const float* __restrict__ bc,
                                                u16* __restrict__ WT2ru,
                                                u16* __restrict__ WT2c){
    const int i = blockIdx.x, g = blockIdx.y, o = threadIdx.x;
    const float* W = (g==0)?Wr:(g==1)?Wu:Wc;
    const float* B = (g==0)?br:(g==1)?bu:bc;
    u16* dst = (g==0)? WT2ru + (size_t)o*K2
             : (g==1)? WT2ru + (size_t)(128+o)*K2
                     : WT2c  + (size_t)o*K2;
    alignas(16) u16 buf[32];
    if (i < IND){
        #pragma unroll
        for (int d = 0; d < 32; ++d) buf[d] = f2bf(W[((size_t)d*IND + i)*HD + o]);
    } else {
        #pragma unroll
        for (int d = 0; d < 32; ++d) buf[d] = f2bf(B[(size_t)d*HD + o]);
    }
    #pragma unroll
    for (int v = 0; v < 4; ++v)
        *reinterpret_cast<uint4*>(dst + i*32 + v*8) = *reinterpret_cast<const uint4*>(&buf[v*8]);
}

// ---------- zero the atomic accumulators (cg|S1|Sc contiguous) -----------------------
__global__ __launch_bounds__(256) void k_zero(float* __restrict__ p){
    reinterpret_cast<float4*>(p)[blockIdx.x*256 + threadIdx.x] = float4{0.f,0.f,0.f,0.f};
}

// ---------- catT[320][4096] bf16 ------------------------------------------------------
__global__ __launch_bounds__(256) void k_pack_catT(const float* __restrict__ x,
                                                   const float* __restrict__ h,
                                                   u16* __restrict__ catT){
    const int t = blockIdx.x*256 + threadIdx.x;
    const int c = blockIdx.y;
    const int k = t*8;
    alignas(16) u16 o[8];
    #pragma unroll
    for (int i = 0; i < 8; ++i){
        int node = k + i;
        float v = (c < XD) ? x[(size_t)node*XD + c]
                : (c < IND) ? h[(size_t)node*HD + (c - XD)] : 0.f;
        o[i] = f2bf(v);
    }
    *reinterpret_cast<uint4*>(catT + (size_t)c*NN + k) = *reinterpret_cast<const uint4*>(o);
}

// ---------- conv MFMA GEMM (split-K=8, XCD-grouped): cg += adj[idx,:] @ catT^T -------
// 1-D grid 1280. Blocks sharing (m-tile, k-split) [the 5 n-tiles] land on one XCD so
// the 64 adj rows are fetched from HBM once per group, then served from that XCD's L2.
__global__ __launch_bounds__(256) void k_conv_mfma(const float* __restrict__ adj,
                                                   const u16* __restrict__ catT,
                                                   const int* __restrict__ idx,
                                                   float* __restrict__ cg){
    __shared__ u16 Asm[64*64];
    __shared__ u16 Bsm[64*64];
    __shared__ int rows[64];
    const int b = blockIdx.x;
    const int xcdr = b & 7, t = b >> 3;
    const int xb = t % 5;                    // n-tile
    const int g  = (t / 5)*8 + xcdr;         // (y,z) group, XCD-resident
    const int yb = g & 31, s = g >> 5;
    const int m0 = yb*64, n0 = xb*64;

    const int tid = threadIdx.x;
    const int wave = tid >> 6, lane = tid & 63;
    if (tid < 64) rows[tid] = idx[m0 + tid];
    __syncthreads();

    const int trow = tid >> 2, kq = (tid & 3)*16;
    const float* arow = adj + (size_t)rows[trow]*NN;
    const int r7 = trow & 7;
    char* aw0 = (char*)Asm + trow*128 + (((kq*2)      ) ^ (r7<<4));
    char* aw1 = (char*)Asm + trow*128 + (((kq*2) + 16 ) ^ (r7<<4));

    const int sw = (((lane&7) ^ (lane>>3)) << 4);
    const char* pB = (const char*)catT + (size_t)(n0 + wave*16 + (lane>>3))*(NN*2) + sw;
    char* lB = (char*)Bsm + wave*2048;

    const int la = lane & 15, lh = lane >> 4;
    const int wr = wave >> 1, wc = wave & 1;
    f32x4 acc[2][2] = {};

    for (int k0 = s*512; k0 < s*512 + 512; k0 += 64){
        gload16(pB + (size_t)k0*2,                    lB);
        gload16(pB + (size_t)k0*2 + (size_t)8*(NN*2), lB + 1024);
        alignas(16) u16 tmp[16];
        #pragma unroll
        for (int v = 0; v < 4; ++v){
            float4 f = *reinterpret_cast<const float4*>(arow + k0 + kq + v*4);
            tmp[v*4+0] = f2bf(f.x); tmp[v*4+1] = f2bf(f.y);
            tmp[v*4+2] = f2bf(f.z); tmp[v*4+3] = f2bf(f.w);
        }
        *reinterpret_cast<uint4*>(aw0) = *reinterpret_cast<const uint4*>(&tmp[0]);
        *reinterpret_cast<uint4*>(aw1) = *reinterpret_cast<const uint4*>(&tmp[8]);
        __syncthreads();
        #pragma unroll
        for (int ks = 0; ks < 2; ++ks){
            const int kb = ks*64 + lh*16;
            bf16x8 a0 = lds_read8(Asm, (wr*32 +  0 + la)*128 + (kb ^ ((la&7)<<4)));
            bf16x8 a1 = lds_read8(Asm, (wr*32 + 16 + la)*128 + (kb ^ ((la&7)<<4)));
            bf16x8 b0 = lds_read8(Bsm, (wc*32 +  0 + la)*128 + (kb ^ ((la&7)<<4)));
            bf16x8 b1 = lds_read8(Bsm, (wc*32 + 16 + la)*128 + (kb ^ ((la&7)<<4)));
            acc[0][0] = __builtin_amdgcn_mfma_f32_16x16x32_bf16(a0, b0, acc[0][0], 0, 0, 0);
            acc[0][1] = __builtin_amdgcn_mfma_f32_16x16x32_bf16(a0, b1, acc[0][1], 0, 0, 0);
            acc[1][0] = __builtin_amdgcn_mfma_f32_16x16x32_bf16(a1, b0, acc[1][0], 0, 0, 0);
            acc[1][1] = __builtin_amdgcn_mfma_f32_16x16x32_bf16(a1, b1, acc[1][1], 0, 0, 0);
        }
        __syncthreads();
    }
    #pragma unroll
    for (int fr = 0; fr < 2; ++fr)
        #pragma unroll
        for (int fc = 0; fc < 2; ++fc){
            int m = m0 + wr*32 + fr*16 + lh*4;
            int n = n0 + wc*32 + fc*16 + la;
            #pragma unroll
            for (int j = 0; j < 4; ++j)
                atomicAdd(&cg[(size_t)(m+j)*CATP + n], acc[fr][fc][j]);
        }
}

// ---------- fused gate GEMM: S += (q ⊗ feat) @ WT2^T, A built on the fly -------------
// 1-D grid, XCD-grouped by n-tile (LG = log2 of XCDs sharing one n-tile).
// Double-buffered B with counted vmcnt + raw s_barrier (no per-step counter drain).
template<int LG>
__global__ __launch_bounds__(256) void k_gate_fused(const float* __restrict__ feat,
                                                    const float* __restrict__ q,
                                                    const u16* __restrict__ WT2,
                                                    float* __restrict__ S, int N){
    __shared__ float featLds[33*64];
    __shared__ u16 Bsm[2][64*32];
    const int b = blockIdx.x;
    const int xcdr = b & 7, t = b >> 3;
    const int xb  = xcdr >> LG;
    const int sub = xcdr & ((1<<LG)-1);
    const int yb  = t & 31;
    const int z   = ((t >> 5) << LG) | sub;
    const int m0 = yb*64, n0 = xb*64;
    const int i0 = z*32 + (z < 2 ? z : 2);
    const int cnt = (z < 2) ? 33 : 32;

    const int tid = threadIdx.x;
    const int wave = tid >> 6, lane = tid & 63;
    const int la = lane & 15, lh = lane >> 4;

    // fill featLds[il][row] = feat[m0+row][i0+il], inject 1.0 at i==257
    {
        const int row = tid >> 2, iq = tid & 3;
        #pragma unroll
        for (int j = 0; j < 9; ++j){
            int il = j*4 + iq;
            if (il < cnt){
                int gi = i0 + il;
                featLds[il*64 + row] = (gi == IND) ? 1.0f
                                     : feat[(size_t)(m0 + row)*CATP + gi];
            }
        }
    }
    // q fragments (once)
    const int wr = wave >> 1, wc = wave & 1;
    const int r0l = wr*32 + la, r1l = r0l + 16;
    const float* q0p = q + (size_t)(m0 + r0l)*QDIM + lh*8;
    const float* q1p = q + (size_t)(m0 + r1l)*QDIM + lh*8;
    float q80[8], q81[8];
    *reinterpret_cast<float4*>(&q80[0]) = *reinterpret_cast<const float4*>(q0p);
    *reinterpret_cast<float4*>(&q80[4]) = *reinterpret_cast<const float4*>(q0p + 4);
    *reinterpret_cast<float4*>(&q81[0]) = *reinterpret_cast<const float4*>(q1p);
    *reinterpret_cast<float4*>(&q81[4]) = *reinterpret_cast<const float4*>(q1p + 4);

    // B staging: dest (col cc, slot lane&3) holds k-chunk (lane&3)^((cc>>1)&3)
    const int cc = tid >> 2;
    const int jj = (lane & 3) ^ ((cc >> 1) & 3);
    const u16* pB = WT2 + (size_t)(n0 + cc)*K2 + jj*8;
    char* lB0 = (char*)&Bsm[0][0] + wave*1024;
    char* lB1 = (char*)&Bsm[1][0] + wave*1024;

    const int col0 = wc*32 + la, col1 = col0 + 16;
    const int b0off = col0*64 + ((lh ^ ((col0>>1)&3)) << 4);
    const int b1off = col1*64 + ((lh ^ ((col1>>1)&3)) << 4);

    f32x4 acc[2][2] = {};

    // drain q/feat loads so vmcnt tracks only staging loads from here on
    asm volatile("s_waitcnt vmcnt(0)" ::: "memory");
    __syncthreads();                          // featLds ready
    gload16(pB + (size_t)i0*32, lB0);         // prologue: step 0 in flight

    for (int s = 0; s < cnt; ++s){
        if (s + 1 < cnt){
            gload16(pB + (size_t)(i0 + s + 1)*32, (s & 1) ? lB0 : lB1);
            asm volatile("s_waitcnt vmcnt(1)" ::: "memory");   // step-s data landed
        } else {
            asm volatile("s_waitcnt vmcnt(0)" ::: "memory");
        }
        __builtin_amdgcn_sched_barrier(0);
        __builtin_amdgcn_s_barrier();         // all waves' step-s quarter landed
        float f0 = featLds[s*64 + r0l];
        float f1 = featLds[s*64 + r1l];
        bf16x8 a0 = mk_afrag(q80, f0);
        bf16x8 a1 = mk_afrag(q81, f1);
        const char* base = (const char*)&Bsm[s & 1][0];
        bf16x8 b0 = lds_read8(base, b0off);
        bf16x8 b1 = lds_read8(base, b1off);
        acc[0][0] = __builtin_amdgcn_mfma_f32_16x16x32_bf16(a0, b0, acc[0][0], 0, 0, 0);
        acc[0][1] = __builtin_amdgcn_mfma_f32_16x16x32_bf16(a0, b1, acc[0][1], 0, 0, 0);
        acc[1][0] = __builtin_amdgcn_mfma_f32_16x16x32_bf16(a1, b0, acc[1][0], 0, 0, 0);
        acc[1][1] = __builtin_amdgcn_mfma_f32_16x16x32_bf16(a1, b1, acc[1][1], 0, 0, 0);
        __builtin_amdgcn_s_barrier();         // reads of Bsm[s&1] done before next overwrite
        __builtin_amdgcn_sched_barrier(0);
    }
    #pragma unroll
    for (int fr = 0; fr < 2; ++fr)
        #pragma unroll
        for (int fc = 0; fc < 2; ++fc){
            int m = m0 + wr*32 + fr*16 + lh*4;
            int n = n0 + wc*32 + fc*16 + la;
            #pragma unroll
            for (int j = 0; j < 4; ++j)
                atomicAdd(&S[(size_t)(m+j)*N + n], acc[fr][fc][j]);
        }
}

// ---------- act1: r,u = sigmoid(S1); featf2 = [x[idx], r*h[idx]]; u_ws = u -----------
__global__ __launch_bounds__(256) void k_act1(const float* __restrict__ S1,
                                              const float* __restrict__ h,
                                              const float* __restrict__ x,
                                              const int* __restrict__ idx,
                                              float* __restrict__ featf2,
                                              float* __restrict__ u_ws){
    const int n = blockIdx.x, t = threadIdx.x;
    const int row = idx[n];
    if (t < HD){
        float rr = 1.f/(1.f + expf(-S1[(size_t)n*256 + t]));
        float uu = 1.f/(1.f + expf(-S1[(size_t)n*256 + 128 + t]));
        featf2[(size_t)n*CATP + XD + t] = rr * h[(size_t)row*HD + t];
        u_ws[(size_t)n*HD + t] = uu;
    }
    if (t < XD) featf2[(size_t)n*CATP + t] = x[(size_t)row*XD + t];
}

// ---------- act2: out = (1-u)*h_upd + u*tanh(Sc); h_upd lives in featf2 --------------
__global__ __launch_bounds__(256) void k_act2(const float* __restrict__ Sc,
                                              const float* __restrict__ featf2,
                                              const float* __restrict__ u_ws,
                                              float* __restrict__ out){
    int id = blockIdx.x*256 + threadIdx.x;
    int n = id >> 7, o = id & 127;
    float hupd = featf2[(size_t)n*CATP + XD + o];
    float uu = u_ws[id];
    out[id] = (1.f - uu)*hupd + uu*tanhf(Sc[id]);
}

extern "C" void kernel_launch(void* const* d_in, const int* in_sizes, int n_in,
                              void* d_out, int out_size, void* d_ws, size_t ws_size,
                              hipStream_t stream) {
    (void)in_sizes; (void)n_in; (void)out_size; (void)ws_size;
    const float* x   = (const float*)d_in[0];
    const float* h   = (const float*)d_in[1];
    const float* q   = (const float*)d_in[2];
    const float* adj = (const float*)d_in[3];
    const int*   idx = (const int*)d_in[4];
    const float* Wu  = (const float*)d_in[5];
    const float* bu  = (const float*)d_in[6];
    const float* Wr  = (const float*)d_in[7];
    const float* br  = (const float*)d_in[8];
    const float* Wc  = (const float*)d_in[9];
    const float* bc  = (const float*)d_in[10];
    float* out = (float*)d_out;

    char* wsb = (char*)d_ws;
    u16*   catT   = (u16*)  (wsb + 0);           // 320*4096*2  = 2,621,440
    u16*   WT2ru  = (u16*)  (wsb + 2621440);     // 256*8256*2  = 4,227,072
    u16*   WT2c   = (u16*)  (wsb + 6848512);     // 128*8256*2  = 2,113,536
    float* cg     = (float*)(wsb + 8962048);     // 2048*320*4  = 2,621,440  ┐
    float* S1     = (float*)(wsb + 11583488);    // 2048*256*4  = 2,097,152  ├ zeroed together
    float* Sc     = (float*)(wsb + 13680640);    // 2048*128*4  = 1,048,576  ┘
    float* featf2 = (float*)(wsb + 14729216);    // 2048*320*4  = 2,621,440
    float* u_ws   = (float*)(wsb + 17350656);    // 2048*128*4  = 1,048,576  (end ~18.4 MB)

    k_cvt_w2       <<<dim3(NSTEP, 3), 128, 0, stream>>>(Wr, Wu, Wc, br, bu, bc, WT2ru, WT2c);
    k_zero         <<<dim3(1408),     256, 0, stream>>>(cg);   // cg|S1|Sc = 5,767,168 B
    k_pack_catT    <<<dim3(2, CATP),  256, 0, stream>>>(x, h, catT);
    k_conv_mfma    <<<dim3(1280),     256, 0, stream>>>(adj, catT, idx, cg);
    k_gate_fused<1><<<dim3(1024),     256, 0, stream>>>(cg, q, WT2ru, S1, 256);
    k_act1         <<<dim3(MQ),       256, 0, stream>>>(S1, h, x, idx, featf2, u_ws);
    k_gate_fused<2><<<dim3(512),      256, 0, stream>>>(featf2, q, WT2c, Sc, 128);
    k_act2         <<<dim3(MQ*HD/256),256, 0, stream>>>(Sc, featf2, u_ws, out);
}